// Round 6
// baseline (555.764 us; speedup 1.0000x reference)
//
#include <hip/hip_runtime.h>
#include <stdint.h>

// ---------------------------------------------------------------------------
// Problem constants
// ---------------------------------------------------------------------------
#define NB   7
#define SIN  16
#define DD   128
#define BB   32
#define TT   2048
#define TM   64          // t-rows per block (4 waves, N-split over cols)
#define KMAX 31

#define XWS  24          // x window row stride (ushort); 48B rows
#define ZS   136         // z / bandout / m row stride
#define UF   264         // full-u row stride (256 cols + pad)
#define PS   72          // p row stride
#define PRS  36          // part1 row stride (floats)

// Fragment-linear weight regions (ushort element offsets in ws).
// Every 512-element chunk is one wave B-fragment: [lane(64)][j(8)].
#define O_CWF 0           // [7][ntile 8][kc 16][512]
#define O_W1F 458752      // [7][etile 16][kb 4][512]
#define O_W2F 688128      // [7][dtile 8][kb 8][512]
#define O_PF  917504      // [7][jtile 4][kb 4][512]
#define O_M1F 974848      // [ctile 8][band 7][kc 2][512]
#define O_M2F 1032192     // [kb 4][512]

// prep source-linear region starts
#define SRC_W1  444416    // 7*496*128
#define SRC_W2  673792    // +7*128*256
#define SRC_PJ  903168    // +7*256*128
#define SRC_M1  960512    // +7*128*64
#define SRC_M2  1017856   // +448*128
#define SRC_PAD 1019904   // +128*16
#define SRC_TOT 1034240   // +14336 pad (conv k=496..511 zero)

typedef short v8s __attribute__((ext_vector_type(8)));
typedef float v4f __attribute__((ext_vector_type(4)));

__device__ __forceinline__ unsigned short f2b(float f) {
    unsigned u = __float_as_uint(f);
    u += 0x7fffu + ((u >> 16) & 1u);          // round-to-nearest-even
    return (unsigned short)(u >> 16);
}
__device__ __forceinline__ float gelu_fast(float x) {   // sigmoid approx (FFN1 only;
    return x / (1.f + __expf(-1.702f * x));             // R1/R3: absmax 4.9e-4, safe)
}
__device__ __forceinline__ float gelu_exact(float x) {  // final mix gelu
    return 0.5f * x * (1.f + erff(x * 0.70710678118654752f));
}

// ---------------------------------------------------------------------------
// Weight prep: SOURCE-linear (coalesced reads, scattered 2B writes).
// Thread i reads src element i, computes its fragment-linear destination.
// ---------------------------------------------------------------------------
__global__ __launch_bounds__(256)
void prep_weights(const float* __restrict__ conv_w,
                  const float* __restrict__ ffn_w1,
                  const float* __restrict__ ffn_w2,
                  const float* __restrict__ proj_w,
                  const float* __restrict__ mix_w1,
                  const float* __restrict__ mix_w2,
                  unsigned short* __restrict__ wsb) {
    int i = blockIdx.x * 256 + threadIdx.x;
    if (i >= SRC_TOT) return;
    float v; size_t dst;
    if (i < SRC_W1) {                                    // conv [7][496][128]
        int band = i / 63488, rem = i % 63488;
        int k = rem >> 7, d = rem & 127;
        v = conv_w[i];
        int f = band * 128 + (d & ~15) + (k >> 5);
        dst = O_CWF + (size_t)f * 512 + ((((k >> 3) & 3) * 16 + (d & 15)) << 3) + (k & 7);
    } else if (i < SRC_W2) {                             // ffn_w1 [7][128][256]
        int ii = i - SRC_W1;
        int band = ii >> 15, rem = ii & 32767;
        int k = rem >> 8, e = rem & 255;
        v = ffn_w1[ii];
        int f = band * 64 + ((e >> 4) << 2) + (k >> 5);
        dst = O_W1F + (size_t)f * 512 + ((((k >> 3) & 3) * 16 + (e & 15)) << 3) + (k & 7);
    } else if (i < SRC_PJ) {                             // ffn_w2 [7][256][128]
        int ii = i - SRC_W2;
        int band = ii >> 15, rem = ii & 32767;
        int k = rem >> 7, d = rem & 127;
        v = ffn_w2[ii];
        int f = band * 64 + ((d >> 4) << 3) + (k >> 5);
        dst = O_W2F + (size_t)f * 512 + ((((k >> 3) & 3) * 16 + (d & 15)) << 3) + (k & 7);
    } else if (i < SRC_M1) {                             // proj [7][128][64]
        int ii = i - SRC_PJ;
        int band = ii >> 13, rem = ii & 8191;
        int k = rem >> 6, c = rem & 63;
        v = proj_w[ii];
        int f = band * 16 + ((c >> 4) << 2) + (k >> 5);
        dst = O_PF + (size_t)f * 512 + ((((k >> 3) & 3) * 16 + (c & 15)) << 3) + (k & 7);
    } else if (i < SRC_M2) {                             // mix_w1 [448][128]
        int ii = i - SRC_M1;
        int k = ii >> 7, c = ii & 127;
        v = mix_w1[ii];
        int f = (c >> 4) * 14 + ((k >> 6) << 1) + ((k >> 5) & 1);
        dst = O_M1F + (size_t)f * 512 + ((((k >> 3) & 3) * 16 + (c & 15)) << 3) + (k & 7);
    } else if (i < SRC_PAD) {                            // mix_w2 [128][16]
        int ii = i - SRC_M2;
        int k = ii >> 4, o = ii & 15;
        v = mix_w2[ii];
        int f = k >> 5;
        dst = O_M2F + (size_t)f * 512 + ((((k >> 3) & 3) * 16 + o) << 3) + (k & 7);
    } else {                                             // conv zero pad (k 496..511)
        int ii = i - SRC_PAD;
        int band = ii >> 11, rem = ii & 2047;
        int ntile = rem >> 8, rem2 = rem & 255;
        int kk = rem2 >> 4, l = rem2 & 15;
        v = 0.f;
        int f = band * 128 + ntile * 16 + 15;
        dst = O_CWF + (size_t)f * 512 + (((2 + (kk >> 3)) * 16 + l) << 3) + (kk & 7);
    }
    wsb[dst] = f2b(v);
}

// ---------------------------------------------------------------------------
// Fused main kernel. N-split: wave w owns cols w*32..w*32+31 of every stage.
// Single-barrier dual-LN (6 row-sums + 5 band-scalars); full-u FFN2 (K=256);
// one-stage-ahead weight prefetch (loads issued before the barrier that
// precedes their use). 5 barriers per band.
// __launch_bounds__(256,2): R2/R4 showed (256,3) splits to ~84 arch VGPRs
// and spills ~1 GB of scratch. DO NOT raise without checking WRITE_SIZE.
// ---------------------------------------------------------------------------
__global__ __launch_bounds__(256, 2)
void fused_main(const float* __restrict__ x,
                const float* __restrict__ conv_b,
                const float* __restrict__ dec_g, const float* __restrict__ dec_b,
                const float* __restrict__ n2_g,  const float* __restrict__ n2_b,
                const float* __restrict__ ffn_b1, const float* __restrict__ ffn_b2,
                const float* __restrict__ proj_b,
                const float* __restrict__ mix_b1, const float* __restrict__ mix_b2,
                const unsigned short* __restrict__ wsb,
                float* __restrict__ out) {
    __shared__ __align__(16) unsigned short xw[95 * XWS];     //  4,560 B
    __shared__ __align__(16) unsigned short zbuf[TM * ZS];    // 17,408 B (z / bandout / m)
    __shared__ __align__(16) unsigned short ubuf[TM * UF];    // 33,792 B (full u; p aliases)
    __shared__ __align__(16) float part1[TM * PRS];           //  9,216 B (6 row-sums x 4 waves)
    __shared__ __align__(16) float bscal[32];                 //    128 B (5 band scalars x 4)

    const int tid  = threadIdx.x;
    const int lane = tid & 63;
    const int w    = tid >> 6;       // wave 0..3
    const int l16  = lane & 15;
    const int quad = lane >> 4;      // 0..3
    const int bb   = blockIdx.x >> 5;
    const int t0   = (blockIdx.x & 31) * TM;

    const unsigned short* cwF = wsb + O_CWF + lane * 8;
    const unsigned short* w1F = wsb + O_W1F + lane * 8;
    const unsigned short* w2F = wsb + O_W2F + lane * 8;
    const unsigned short* pF  = wsb + O_PF  + lane * 8;
    const unsigned short* m1F = wsb + O_M1F + lane * 8;
    const unsigned short* m2F = wsb + O_M2F + lane * 8;

    // ---- S0: stage x window (rows t0-15 .. t0+78), bf16 ----
    for (int i = tid; i < 95 * SIN; i += 256) {
        int r = i >> 4, s = i & 15;
        int t = t0 + r - 15;
        float v = (t >= 0 && t < TT) ? x[((long)bb * TT + t) * SIN + s] : 0.f;
        xw[r * XWS + s] = f2b(v);
    }

    v4f macc[4][2];                  // persistent mix1 accumulators (ctiles 2w,2w+1)
    #pragma unroll
    for (int mt = 0; mt < 4; mt++)
        #pragma unroll
        for (int c = 0; c < 2; c++) macc[mt][c] = (v4f){0.f, 0.f, 0.f, 0.f};

    __syncthreads();

    static const int lo_kc[NB] = {0, 2, 4, 5, 6, 6, 7};
    static const int hi_kc[NB] = {16, 13, 12, 11, 10, 9, 9};

    const int col0 = w * 32 + l16;
    const int col1 = col0 + 16;

    for (int n = 0; n < NB; ++n) {
        unsigned hpk[16];            // packed hn residual
        v4f acc[4][2];
        #pragma unroll
        for (int mt = 0; mt < 4; mt++)
            #pragma unroll
            for (int c = 0; c < 2; c++) acc[mt][c] = (v4f){0.f, 0.f, 0.f, 0.f};

        // ===== conv im2col GEMM (M=64, N=32/wave), SW-pipelined over kc =====
        {
            const int lo = lo_kc[n], hi = hi_kc[n];
            const unsigned short* cw0 = cwF + ((size_t)((n * 8 + 2 * w)     * 16)) * 512;
            const unsigned short* cw1 = cwF + ((size_t)((n * 8 + 2 * w + 1) * 16)) * 512;
            const int scol = (quad & 1) * 8;
            v8s b0a = *reinterpret_cast<const v8s*>(cw0 + (size_t)lo * 512);
            v8s b0b = *reinterpret_cast<const v8s*>(cw1 + (size_t)lo * 512);
            for (int kc = lo; kc < hi; ++kc) {
                v8s b1a, b1b;
                if (kc + 1 < hi) {
                    b1a = *reinterpret_cast<const v8s*>(cw0 + (size_t)(kc + 1) * 512);
                    b1b = *reinterpret_cast<const v8s*>(cw1 + (size_t)(kc + 1) * 512);
                }
                const int tap = kc * 2 + (quad >> 1);
                #pragma unroll
                for (int mt = 0; mt < 4; mt++) {
                    v8s a = *reinterpret_cast<const v8s*>(&xw[(mt * 16 + l16 + tap) * XWS + scol]);
                    acc[mt][0] = __builtin_amdgcn_mfma_f32_16x16x32_bf16(a, b0a, acc[mt][0], 0, 0, 0);
                    acc[mt][1] = __builtin_amdgcn_mfma_f32_16x16x32_bf16(a, b0b, acc[mt][1], 0, 0, 0);
                }
                b0a = b1a; b0b = b1b;
            }
        }

        // ===== band scalars + 6 LN row-sum partials (ONE reduction pass) =====
        const float g0 = dec_g[n * 128 + col0], g1 = dec_g[n * 128 + col1];
        const float d0 = dec_b[n * 128 + col0], d1 = dec_b[n * 128 + col1];
        {
            float sg = g0 + g1, sg2 = g0 * g0 + g1 * g1, sgb = g0 * d0 + g1 * d1;
            float sb = d0 + d1, sb2 = d0 * d0 + d1 * d1;
            #pragma unroll
            for (int m = 1; m <= 8; m <<= 1) {
                sg += __shfl_xor(sg, m); sg2 += __shfl_xor(sg2, m);
                sgb += __shfl_xor(sgb, m); sb += __shfl_xor(sb, m);
                sb2 += __shfl_xor(sb2, m);
            }
            if (lane == 0) {
                bscal[w * 8 + 0] = sg;  bscal[w * 8 + 1] = sg2;
                bscal[w * 8 + 2] = sgb; bscal[w * 8 + 3] = sb;
                bscal[w * 8 + 4] = sb2;
            }
        }
        {
            const float cb0 = conv_b[n * 128 + col0];
            const float cb1 = conv_b[n * 128 + col1];
            #pragma unroll
            for (int mt = 0; mt < 4; mt++)
                #pragma unroll
                for (int r = 0; r < 4; r++) {
                    float h0 = acc[mt][0][r] + cb0;
                    float h1 = acc[mt][1][r] + cb1;
                    acc[mt][0][r] = h0; acc[mt][1][r] = h1;
                    float gh0 = g0 * h0, gh1 = g1 * h1;
                    float p0 = h0 + h1, p1 = h0 * h0 + h1 * h1;
                    float p2 = gh0 + gh1, p3 = g0 * gh0 + g1 * gh1;
                    float p4 = gh0 * gh0 + gh1 * gh1, p5 = d0 * gh0 + d1 * gh1;
                    #pragma unroll
                    for (int m = 1; m <= 8; m <<= 1) {
                        p0 += __shfl_xor(p0, m); p1 += __shfl_xor(p1, m);
                        p2 += __shfl_xor(p2, m); p3 += __shfl_xor(p3, m);
                        p4 += __shfl_xor(p4, m); p5 += __shfl_xor(p5, m);
                    }
                    if (l16 == 0) {
                        const int row = mt * 16 + quad * 4 + r;
                        float* pp = &part1[row * PRS + w * 8];
                        *reinterpret_cast<float2*>(pp)     = float2{p0, p1};
                        *reinterpret_cast<float2*>(pp + 2) = float2{p2, p3};
                        *reinterpret_cast<float2*>(pp + 4) = float2{p4, p5};
                    }
                }
        }
        // prefetch FFN1 eh0 B-frags (land during barrier drain)
        v8s bf1[2][4];
        #pragma unroll
        for (int c = 0; c < 2; c++)
            #pragma unroll
            for (int kb = 0; kb < 4; kb++)
                bf1[c][kb] = *reinterpret_cast<const v8s*>(
                    w1F + ((size_t)((n * 16 + 2 * w + c) * 4 + kb)) * 512);
        __syncthreads();   // B1: partials ready

        // ===== resolve both LNs; write z; pack hn residual =====
        {
            float G1 = 0.f, G2 = 0.f, GB = 0.f, SB = 0.f, SB2 = 0.f;
            #pragma unroll
            for (int ww = 0; ww < 4; ww++) {
                G1 += bscal[ww * 8 + 0]; G2 += bscal[ww * 8 + 1];
                GB += bscal[ww * 8 + 2]; SB += bscal[ww * 8 + 3];
                SB2 += bscal[ww * 8 + 4];
            }
            const float ng0 = n2_g[n * 128 + col0], nb0 = n2_b[n * 128 + col0];
            const float ng1 = n2_g[n * 128 + col1], nb1 = n2_b[n * 128 + col1];
            #pragma unroll
            for (int mt = 0; mt < 4; mt++)
                #pragma unroll
                for (int r = 0; r < 4; r++) {
                    const int row = mt * 16 + quad * 4 + r;
                    const float4* pr = reinterpret_cast<const float4*>(&part1[row * PRS]);
                    float4 qa = pr[0], qb = pr[1], qc = pr[2], qd = pr[3];
                    float4 qe = pr[4], qf = pr[5], qg = pr[6], qh = pr[7];
                    float S1 = qa.x + qc.x + qe.x + qg.x;
                    float S2 = qa.y + qc.y + qe.y + qg.y;
                    float Sgh = qa.z + qc.z + qe.z + qg.z;
                    float Sg2h = qa.w + qc.w + qe.w + qg.w;
                    float Sg2h2 = qb.x + qd.x + qf.x + qh.x;
                    float Sgbh = qb.y + qd.y + qf.y + qh.y;
                    float mu = S1 * (1.f / 128.f);
                    float rs = rsqrtf(S2 * (1.f / 128.f) - mu * mu + 1e-5f);
                    float T1 = rs * (Sgh - mu * G1) + SB;
                    float T2 = rs * rs * (Sg2h2 - 2.f * mu * Sg2h + mu * mu * G2)
                             + 2.f * rs * (Sgbh - mu * GB) + SB2;
                    float mu2 = T1 * (1.f / 128.f);
                    float rs2 = rsqrtf(T2 * (1.f / 128.f) - mu2 * mu2 + 1e-5f);
                    float hn0 = (acc[mt][0][r] - mu) * rs * g0 + d0;
                    float hn1 = (acc[mt][1][r] - mu) * rs * g1 + d1;
                    zbuf[row * ZS + col0] = f2b((hn0 - mu2) * rs2 * ng0 + nb0);
                    zbuf[row * ZS + col1] = f2b((hn1 - mu2) * rs2 * ng1 + nb1);
                    hpk[mt * 4 + r] = (unsigned)f2b(hn0) | ((unsigned)f2b(hn1) << 16);
                }
        }
        __syncthreads();   // B2: z ready

        // ===== FFN1 (both e-halves, full u), prefetch FFN2 batch A =====
        v8s bf2a[2][4], bf1b[2][4];
        #pragma unroll
        for (int c = 0; c < 2; c++)                       // eh1 frags: fly during eh0 MFMAs
            #pragma unroll
            for (int kb = 0; kb < 4; kb++)
                bf1b[c][kb] = *reinterpret_cast<const v8s*>(
                    w1F + ((size_t)((n * 16 + 8 + 2 * w + c) * 4 + kb)) * 512);
        {
            v4f ua[4][2];
            #pragma unroll
            for (int mt = 0; mt < 4; mt++)
                #pragma unroll
                for (int c = 0; c < 2; c++) ua[mt][c] = (v4f){0.f, 0.f, 0.f, 0.f};
            #pragma unroll
            for (int kb = 0; kb < 4; kb++)
                #pragma unroll
                for (int mt = 0; mt < 4; mt++) {
                    v8s a = *reinterpret_cast<const v8s*>(&zbuf[(mt * 16 + l16) * ZS + kb * 32 + quad * 8]);
                    ua[mt][0] = __builtin_amdgcn_mfma_f32_16x16x32_bf16(a, bf1[0][kb], ua[mt][0], 0, 0, 0);
                    ua[mt][1] = __builtin_amdgcn_mfma_f32_16x16x32_bf16(a, bf1[1][kb], ua[mt][1], 0, 0, 0);
                }
            #pragma unroll
            for (int c = 0; c < 2; c++)                   // FFN2 batch A (kb 0..3)
                #pragma unroll
                for (int kb = 0; kb < 4; kb++)
                    bf2a[c][kb] = *reinterpret_cast<const v8s*>(
                        w2F + ((size_t)((n * 8 + 2 * w + c) * 8 + kb)) * 512);
            const float b10 = ffn_b1[n * 256 + w * 32 + l16];
            const float b11 = ffn_b1[n * 256 + w * 32 + 16 + l16];
            #pragma unroll
            for (int mt = 0; mt < 4; mt++)
                #pragma unroll
                for (int r = 0; r < 4; r++) {
                    const int row = mt * 16 + quad * 4 + r;
                    ubuf[row * UF + w * 32 + l16]      = f2b(gelu_fast(ua[mt][0][r] + b10));
                    ubuf[row * UF + w * 32 + 16 + l16] = f2b(gelu_fast(ua[mt][1][r] + b11));
                }
            // eh1
            #pragma unroll
            for (int mt = 0; mt < 4; mt++)
                #pragma unroll
                for (int c = 0; c < 2; c++) ua[mt][c] = (v4f){0.f, 0.f, 0.f, 0.f};
            #pragma unroll
            for (int kb = 0; kb < 4; kb++)
                #pragma unroll
                for (int mt = 0; mt < 4; mt++) {
                    v8s a = *reinterpret_cast<const v8s*>(&zbuf[(mt * 16 + l16) * ZS + kb * 32 + quad * 8]);
                    ua[mt][0] = __builtin_amdgcn_mfma_f32_16x16x32_bf16(a, bf1b[0][kb], ua[mt][0], 0, 0, 0);
                    ua[mt][1] = __builtin_amdgcn_mfma_f32_16x16x32_bf16(a, bf1b[1][kb], ua[mt][1], 0, 0, 0);
                }
            const float b12 = ffn_b1[n * 256 + 128 + w * 32 + l16];
            const float b13 = ffn_b1[n * 256 + 128 + w * 32 + 16 + l16];
            #pragma unroll
            for (int mt = 0; mt < 4; mt++)
                #pragma unroll
                for (int r = 0; r < 4; r++) {
                    const int row = mt * 16 + quad * 4 + r;
                    ubuf[row * UF + 128 + w * 32 + l16]      = f2b(gelu_fast(ua[mt][0][r] + b12));
                    ubuf[row * UF + 128 + w * 32 + 16 + l16] = f2b(gelu_fast(ua[mt][1][r] + b13));
                }
        }
        __syncthreads();   // B3: full u ready

        // ===== FFN2 K=256 single pass + residual -> zbuf =====
        {
            v8s bf2b[2][4];
            #pragma unroll
            for (int c = 0; c < 2; c++)
                #pragma unroll
                for (int kb = 0; kb < 4; kb++)
                    bf2b[c][kb] = *reinterpret_cast<const v8s*>(
                        w2F + ((size_t)((n * 8 + 2 * w + c) * 8 + 4 + kb)) * 512);
            v4f acc2[4][2];
            #pragma unroll
            for (int mt = 0; mt < 4; mt++)
                #pragma unroll
                for (int c = 0; c < 2; c++) acc2[mt][c] = (v4f){0.f, 0.f, 0.f, 0.f};
            #pragma unroll
            for (int kb = 0; kb < 4; kb++)
                #pragma unroll
                for (int mt = 0; mt < 4; mt++) {
                    v8s a = *reinterpret_cast<const v8s*>(&ubuf[(mt * 16 + l16) * UF + kb * 32 + quad * 8]);
                    acc2[mt][0] = __builtin_amdgcn_mfma_f32_16x16x32_bf16(a, bf2a[0][kb], acc2[mt][0], 0, 0, 0);
                    acc2[mt][1] = __builtin_amdgcn_mfma_f32_16x16x32_bf16(a, bf2a[1][kb], acc2[mt][1], 0, 0, 0);
                }
            #pragma unroll
            for (int kb = 0; kb < 4; kb++)
                #pragma unroll
                for (int mt = 0; mt < 4; mt++) {
                    v8s a = *reinterpret_cast<const v8s*>(&ubuf[(mt * 16 + l16) * UF + 128 + kb * 32 + quad * 8]);
                    acc2[mt][0] = __builtin_amdgcn_mfma_f32_16x16x32_bf16(a, bf2b[0][kb], acc2[mt][0], 0, 0, 0);
                    acc2[mt][1] = __builtin_amdgcn_mfma_f32_16x16x32_bf16(a, bf2b[1][kb], acc2[mt][1], 0, 0, 0);
                }
            const float b20 = ffn_b2[n * 128 + col0];
            const float b21 = ffn_b2[n * 128 + col1];
            #pragma unroll
            for (int mt = 0; mt < 4; mt++)
                #pragma unroll
                for (int r = 0; r < 4; r++) {
                    const int row = mt * 16 + quad * 4 + r;
                    unsigned hp = hpk[mt * 4 + r];
                    float hn0 = __uint_as_float(hp << 16);
                    float hn1 = __uint_as_float(hp & 0xffff0000u);
                    zbuf[row * ZS + col0] = f2b(acc2[mt][0][r] + b20 + hn0);
                    zbuf[row * ZS + col1] = f2b(acc2[mt][1][r] + b21 + hn1);
                }
        }
        // prefetch proj frags
        v8s bfp[4];
        #pragma unroll
        for (int kb = 0; kb < 4; kb++)
            bfp[kb] = *reinterpret_cast<const v8s*>(
                pF + ((size_t)((n * 4 + w) * 4 + kb)) * 512);
        __syncthreads();   // B4: bandout ready

        // ===== proj (M=64, N=16/wave, K=128) -> p in ubuf =====
        {
            v4f pa[4];
            #pragma unroll
            for (int mt = 0; mt < 4; mt++) pa[mt] = (v4f){0.f, 0.f, 0.f, 0.f};
            #pragma unroll
            for (int kb = 0; kb < 4; kb++)
                #pragma unroll
                for (int mt = 0; mt < 4; mt++) {
                    v8s a = *reinterpret_cast<const v8s*>(&zbuf[(mt * 16 + l16) * ZS + kb * 32 + quad * 8]);
                    pa[mt] = __builtin_amdgcn_mfma_f32_16x16x32_bf16(a, bfp[kb], pa[mt], 0, 0, 0);
                }
            const float pbv = proj_b[n * 64 + w * 16 + l16];
            unsigned short* pb = ubuf;   // alias (u dead)
            #pragma unroll
            for (int mt = 0; mt < 4; mt++)
                #pragma unroll
                for (int r = 0; r < 4; r++)
                    pb[(mt * 16 + quad * 4 + r) * PS + w * 16 + l16] = f2b(pa[mt][r] + pbv);
        }
        // prefetch mix1 frags
        v8s bfm[2][2];
        #pragma unroll
        for (int c = 0; c < 2; c++)
            #pragma unroll
            for (int kc = 0; kc < 2; kc++)
                bfm[c][kc] = *reinterpret_cast<const v8s*>(
                    m1F + ((size_t)(((2 * w + c) * 7 + n) * 2 + kc)) * 512);
        __syncthreads();   // B5: p ready

        // ===== mix1 partial accumulate (K=64) =====
        {
            const unsigned short* pb = ubuf;
            #pragma unroll
            for (int kc = 0; kc < 2; kc++)
                #pragma unroll
                for (int mt = 0; mt < 4; mt++) {
                    v8s a = *reinterpret_cast<const v8s*>(&pb[(mt * 16 + l16) * PS + kc * 32 + quad * 8]);
                    macc[mt][0] = __builtin_amdgcn_mfma_f32_16x16x32_bf16(a, bfm[0][kc], macc[mt][0], 0, 0, 0);
                    macc[mt][1] = __builtin_amdgcn_mfma_f32_16x16x32_bf16(a, bfm[1][kc], macc[mt][1], 0, 0, 0);
                }
        }
        // no barrier: next writes (part1/bscal/zbuf) are >=2 barriers from last reads
    }

    // ===== m = gelu_exact(macc + b1) -> zbuf =====
    #pragma unroll
    for (int c = 0; c < 2; c++) {
        const int col = (2 * w + c) * 16 + l16;
        const float mb1 = mix_b1[col];
        #pragma unroll
        for (int mt = 0; mt < 4; mt++)
            #pragma unroll
            for (int r = 0; r < 4; r++)
                zbuf[(mt * 16 + quad * 4 + r) * ZS + col] = f2b(gelu_exact(macc[mt][c][r] + mb1));
    }
    __syncthreads();

    // ===== mix2 (M=16/wave, N=16, K=128) -> out =====
    {
        v8s bf[4];
        #pragma unroll
        for (int kb = 0; kb < 4; kb++)
            bf[kb] = *reinterpret_cast<const v8s*>(m2F + (size_t)kb * 512);
        v4f oacc = (v4f){0.f, 0.f, 0.f, 0.f};
        #pragma unroll
        for (int kb = 0; kb < 4; kb++) {
            v8s a = *reinterpret_cast<const v8s*>(&zbuf[(w * 16 + l16) * ZS + kb * 32 + quad * 8]);
            oacc = __builtin_amdgcn_mfma_f32_16x16x32_bf16(a, bf[kb], oacc, 0, 0, 0);
        }
        const float ob = mix_b2[l16];
        #pragma unroll
        for (int r = 0; r < 4; r++) {
            const int row = w * 16 + quad * 4 + r;
            out[((long)bb * TT + t0 + row) * SIN + l16] = oacc[r] + ob;
        }
    }
}

// ---------------------------------------------------------------------------
extern "C" void kernel_launch(void* const* d_in, const int* in_sizes, int n_in,
                              void* d_out, int out_size, void* d_ws, size_t ws_size,
                              hipStream_t stream) {
    (void)in_sizes; (void)n_in; (void)out_size; (void)ws_size;
    const float* x      = (const float*)d_in[0];
    const float* conv_w = (const float*)d_in[1];
    const float* conv_b = (const float*)d_in[2];
    const float* dec_g  = (const float*)d_in[3];
    const float* dec_b  = (const float*)d_in[4];
    const float* n2_g   = (const float*)d_in[5];
    const float* n2_b   = (const float*)d_in[6];
    const float* ffn_w1 = (const float*)d_in[7];
    const float* ffn_b1 = (const float*)d_in[8];
    const float* ffn_w2 = (const float*)d_in[9];
    const float* ffn_b2 = (const float*)d_in[10];
    const float* proj_w = (const float*)d_in[11];
    const float* proj_b = (const float*)d_in[12];
    const float* mix_w1 = (const float*)d_in[13];
    const float* mix_b1 = (const float*)d_in[14];
    const float* mix_w2 = (const float*)d_in[15];
    const float* mix_b2 = (const float*)d_in[16];
    unsigned short* wsb = (unsigned short*)d_ws;
    float* out = (float*)d_out;

    hipLaunchKernelGGL(prep_weights, dim3((SRC_TOT + 255) / 256), dim3(256), 0, stream,
                       conv_w, ffn_w1, ffn_w2, proj_w, mix_w1, mix_w2, wsb);
    hipLaunchKernelGGL(fused_main, dim3(BB * (TT / TM)), dim3(256), 0, stream,
                       x, conv_b, dec_g, dec_b, n2_g, n2_b, ffn_b1, ffn_b2,
                       proj_b, mix_b1, mix_b2, wsb, out);
}